// Round 5
// baseline (131812.439 us; speedup 1.0000x reference)
//
#include <hip/hip_runtime.h>
#include <cstdint>
#include <cstddef>

#define H   1024
#define V   32000
#define L   2048
#define G4  4096      // 4*H
#define NB  256       // blocks (1 per CU, co-resident)
#define NT  1024      // threads per block (16 waves of 64)
#define RPB (V / NB)  // 125 FC rows per block

// final-GEMM config
#define GNB   500     // 32000 / 64 rows per block
#define GT    512     // threads (8 waves)
#define GS    8       // steps per chunk
#define GR    8       // rows per wave
#define NCHUNK (L / GS)  // 256

// ---------------------------------------------------------------------------
__device__ __forceinline__ float wave_reduce_sum(float v) {
    #pragma unroll
    for (int off = 32; off > 0; off >>= 1) v += __shfl_down(v, off);
    return v;
}

__device__ __forceinline__ float wave_reduce_max(float v) {
    #pragma unroll
    for (int off = 32; off > 0; off >>= 1) v = fmaxf(v, __shfl_down(v, off));
    return v;
}

__device__ __forceinline__ unsigned long long wave_reduce_max_u64(unsigned long long v) {
    #pragma unroll
    for (int off = 32; off > 0; off >>= 1) {
        const unsigned long long o = __shfl_down(v, off);
        v = (o > v) ? o : v;
    }
    return v;
}

__device__ __forceinline__ float sigmoidf_(float x) {
    return 1.0f / (1.0f + expf(-x));
}

__device__ __forceinline__ float dot4(const float4 w, const float* __restrict__ h, int c) {
    return w.x * h[c] + w.y * h[c + 1] + w.z * h[c + 2] + w.w * h[c + 3];
}

// sign-extend byte `pos` of dword w to float
__device__ __forceinline__ float sb2f(int w, int pos) {
    return (float)((w << ((3 - pos) * 8)) >> 24);
}

// ---------------------------------------------------------------------------
// Per-access device-coherent loads/stores (sc0|sc1 flagged, RELAXED).
// Line-granular: they do NOT invalidate/flush the XCD L2, so the weight
// working set stays cached across grid barriers (R1's failure was
// agent-scope acquire/release fences emitting buffer_inv every barrier).
// ---------------------------------------------------------------------------
__device__ __forceinline__ float ldc(const float* p) {
    return __hip_atomic_load(p, __ATOMIC_RELAXED, __HIP_MEMORY_SCOPE_AGENT);
}
__device__ __forceinline__ void stc(float* p, float v) {
    __hip_atomic_store(p, v, __ATOMIC_RELAXED, __HIP_MEMORY_SCOPE_AGENT);
}
__device__ __forceinline__ unsigned long long ldc64(const unsigned long long* p) {
    return __hip_atomic_load(p, __ATOMIC_RELAXED, __HIP_MEMORY_SCOPE_AGENT);
}
__device__ __forceinline__ void stc64(unsigned long long* p, unsigned long long v) {
    __hip_atomic_store(p, v, __ATOMIC_RELAXED, __HIP_MEMORY_SCOPE_AGENT);
}

// ---------------------------------------------------------------------------
// Fence-free grid barrier, monotonic counter (target = NB * barrier_index).
// Correctness: each wave's __syncthreads drains its VMEM (vmcnt(0)) — the
// preceding sc1 stores are at the device coherence point before thread 0
// adds to the counter. Readers spin read-only (no RMW contention), with
// s_sleep backoff. No threadfence => no buffer_inv => L2 stays warm.
// ---------------------------------------------------------------------------
__device__ __forceinline__ void gbar(unsigned int* cnt, unsigned int target) {
    __syncthreads();
    if (threadIdx.x == 0) {
        __hip_atomic_fetch_add(cnt, 1u, __ATOMIC_RELAXED, __HIP_MEMORY_SCOPE_AGENT);
        while (__hip_atomic_load(cnt, __ATOMIC_RELAXED, __HIP_MEMORY_SCOPE_AGENT) < target)
            __builtin_amdgcn_s_sleep(4);
    }
    __syncthreads();
}

// ---------------------------------------------------------------------------
// One-time: w_fc fp32 -> per-row-scaled int8 + exact quant-error L2 norm.
// scl_eps[row] = {scale, ||w_row - scale*q_row||_2}.
// ---------------------------------------------------------------------------
__global__ __launch_bounds__(256) void quant_fc(
    const float* __restrict__ src, signed char* __restrict__ dst,
    float2* __restrict__ scl_eps)
{
    const int gw   = (blockIdx.x * blockDim.x + threadIdx.x) >> 6;
    const int lane = threadIdx.x & 63;
    const int nw   = (gridDim.x * blockDim.x) >> 6;
    for (int row = gw; row < V; row += nw) {
        const float* p = src + (size_t)row * H + lane * 16;
        float w[16];
        #pragma unroll
        for (int j = 0; j < 4; j++) {
            const float4 f = *(const float4*)(p + j * 4);
            w[j * 4 + 0] = f.x; w[j * 4 + 1] = f.y;
            w[j * 4 + 2] = f.z; w[j * 4 + 3] = f.w;
        }
        float m = 0.f;
        #pragma unroll
        for (int j = 0; j < 16; j++) m = fmaxf(m, fabsf(w[j]));
        m = wave_reduce_max(m);
        m = __shfl(m, 0);
        const float scale = fmaxf(m, 1e-30f) / 127.f;
        const float inv   = 127.f / fmaxf(m, 1e-30f);
        int q[16];
        float esq = 0.f;
        #pragma unroll
        for (int j = 0; j < 16; j++) {
            q[j] = __float2int_rn(w[j] * inv);
            const float e = w[j] - scale * (float)q[j];
            esq += e * e;
        }
        esq = wave_reduce_sum(esq);
        const unsigned int d0 = (q[0] & 255) | ((q[1] & 255) << 8) | ((q[2] & 255) << 16) | ((unsigned int)(q[3] & 255) << 24);
        const unsigned int d1 = (q[4] & 255) | ((q[5] & 255) << 8) | ((q[6] & 255) << 16) | ((unsigned int)(q[7] & 255) << 24);
        const unsigned int d2 = (q[8] & 255) | ((q[9] & 255) << 8) | ((q[10] & 255) << 16) | ((unsigned int)(q[11] & 255) << 24);
        const unsigned int d3 = (q[12] & 255) | ((q[13] & 255) << 8) | ((q[14] & 255) << 16) | ((unsigned int)(q[15] & 255) << 24);
        *(int4*)(dst + (size_t)row * H + lane * 16) =
            make_int4((int)d0, (int)d1, (int)d2, (int)d3);
        if (lane == 0) {
            scl_eps[row] = make_float2(scale, sqrtf(esq) + 1e-12f);
        }
    }
}

// ---------------------------------------------------------------------------
// Persistent kernel: all 2047 steps, 2 fence-free grid barriers per step.
// LSTM weight rows (w_ih1 / w_hh0 / w_hh1) are step-invariant per-thread
// REGISTER state (48 VGPRs) — 48 MB/step of loads removed entirely.
// Math is op-identical to the R3 two-kernel version.
// ---------------------------------------------------------------------------
__global__ __launch_bounds__(NT) void persistent_kernel(
    const int* __restrict__ y, const float* __restrict__ ctx,
    const float* __restrict__ w_ih0, const float* __restrict__ w_ih1,
    const float* __restrict__ w_hh0, const float* __restrict__ w_hh1,
    const float* __restrict__ b_ih0, const float* __restrict__ b_hh0,
    const float* __restrict__ b_ih1, const float* __restrict__ b_hh1,
    const signed char* __restrict__ wq8, const float2* __restrict__ scl_eps,
    const float* __restrict__ w_fc, const float* __restrict__ b_fc,
    float* __restrict__ v0g, float* __restrict__ h1g,
    unsigned long long* __restrict__ keys, unsigned int* __restrict__ cnt,
    float* __restrict__ h1_hist)
{
    __shared__ __align__(16) float h0s[H];
    __shared__ __align__(16) float hcs[H];
    __shared__ float g1s[16];
    __shared__ unsigned long long kred[4];
    __shared__ float lb[128], ub[128];
    __shared__ float red[16];
    __shared__ float LBmax_s;
    __shared__ unsigned long long wkey[16];
    __shared__ float c1s[4];

    const int b = blockIdx.x, t = threadIdx.x;
    const int wave = t >> 6, lane = t & 63;
    const int rowR = (wave >> 2) * H + b * 4 + (wave & 3);

    unsigned int barK = 0;

    // ---- persistent register state: this wave's 3 LSTM weight rows ----
    float4 wu[4], wa[4], wb[4];
    #pragma unroll
    for (int k = 0; k < 4; k++) {
        const int c = k * 256 + lane * 4;
        wu[k] = *(const float4*)(w_hh1 + (size_t)rowR * H + c);
        wa[k] = *(const float4*)(w_ih1 + (size_t)rowR * H + c);
        wb[k] = *(const float4*)(w_hh0 + (size_t)rowR * H + c);
    }
    const float wia = w_ih0[t],         wib = w_ih0[H + t];
    const float wic = w_ih0[2 * H + t], wid = w_ih0[3 * H + t];
    const float bias0 = b_ih0[rowR] + b_hh0[rowR];
    const float bias1 = b_ih1[rowR] + b_hh1[rowR];
    float c0_reg = ctx[t];                 // block-redundant c0 in register

    // ---- prologue: v0 buffer0, accU for step 1, c1, keys seed ----
    h0s[t] = ctx[t];
    hcs[t] = ctx[H + t];
    if (t < 4) c1s[t] = ctx[H + b * 4 + t];
    __syncthreads();
    {
        float accV = 0.f;
        #pragma unroll
        for (int k = 0; k < 4; k++) accV += dot4(wb[k], h0s, k * 256 + lane * 4);
        accV = wave_reduce_sum(accV);
        if (lane == 0) stc(&v0g[rowR], accV + bias0);   // buffer 0
    }
    float accU = 0.f;                      // per-lane u1 partial, carried in reg
    #pragma unroll
    for (int k = 0; k < 4; k++) accU += dot4(wu[k], hcs, k * 256 + lane * 4);
    if (b == 0 && t < NB) {
        const unsigned long long seed =
            ((unsigned long long)0x7F800000u << 32) |
            (0xFFFFFFFFu - (unsigned int)y[0]);
        stc64(&keys[t], (t == 0) ? seed : 0ull);
    }
    gbar(cnt, NB * (++barK));

    // ---------------- main loop ----------------
    for (int step = 1; step < L; ++step) {
        const float* v0i = v0g + ((step - 1) & 1) * G4;
        float*       v0o = v0g + (step & 1) * G4;
        float*       h1c = h1g + (step & 1) * H;

        // ======== phase A: lstm ========
        if (wave < 4) {
            unsigned long long k = ldc64(&keys[t]);     // t < 256
            k = wave_reduce_max_u64(k);
            if (lane == 0) kred[wave] = k;
        }
        const float v0a = ldc(&v0i[t]);
        const float v0b = ldc(&v0i[H + t]);
        const float v0c = ldc(&v0i[2 * H + t]);
        const float v0d = ldc(&v0i[3 * H + t]);
        __syncthreads();

        unsigned long long kk = kred[0];
        kk = (kred[1] > kk) ? kred[1] : kk;
        kk = (kred[2] > kk) ? kred[2] : kk;
        kk = (kred[3] > kk) ? kred[3] : kk;
        const float tok =
            (float)(unsigned int)(0xFFFFFFFFu - (unsigned int)(kk & 0xFFFFFFFFull));

        // cell0 (block-redundant), element j = t; c0 in register
        {
            const float gi = v0a + tok * wia;
            const float gf = v0b + tok * wib;
            const float gg = v0c + tok * wic;
            const float go = v0d + tok * wid;
            const float i_ = sigmoidf_(gi);
            const float f_ = sigmoidf_(gf);
            const float g_ = tanhf(gg);
            const float o_ = sigmoidf_(go);
            const float cn = f_ * c0_reg + i_ * g_;
            c0_reg = cn;
            h0s[t] = o_ * tanhf(cn);
        }
        __syncthreads();

        // per wave: g1 row (reg w_ih1 @ h0 + carried accU), v0 row (reg w_hh0 @ h0)
        {
            float accA = 0.f, accB = 0.f;
            #pragma unroll
            for (int k = 0; k < 4; k++) {
                const int c = k * 256 + lane * 4;
                accA += dot4(wa[k], h0s, c);
                accB += dot4(wb[k], h0s, c);
            }
            const float g  = wave_reduce_sum(accA + accU);
            const float vv = wave_reduce_sum(accB);
            if (lane == 0) {
                g1s[wave] = g + bias1;
                stc(&v0o[rowR], vv + bias0);
            }
        }
        __syncthreads();

        // cell1: this block's 4 elements
        if (t < 4) {
            const float i_ = sigmoidf_(g1s[t]);
            const float f_ = sigmoidf_(g1s[4 + t]);
            const float g_ = tanhf(g1s[8 + t]);
            const float o_ = sigmoidf_(g1s[12 + t]);
            const float cn = f_ * c1s[t] + i_ * g_;
            c1s[t] = cn;
            const float hv = o_ * tanhf(cn);
            stc(&h1c[b * 4 + t], hv);
            h1_hist[(size_t)step * H + b * 4 + t] = hv;
        }
        gbar(cnt, NB * (++barK));

        // ======== phase B: int8 screen + sound rescue ========
        if (t < 128) { lb[t] = -3e38f; ub[t] = -3e38f; }
        const float hv2 = ldc(&h1c[t]);
        hcs[t] = hv2;
        {
            const float sq = wave_reduce_sum(hv2 * hv2);
            if (lane == 0) red[wave] = sq;
        }
        __syncthreads();

        float s = 0.f;
        #pragma unroll
        for (int i = 0; i < 16; i++) s += red[i];
        const float Hl2 = sqrtf(s);

        const float4 hA = *(const float4*)(hcs + lane * 16);
        const float4 hB = *(const float4*)(hcs + lane * 16 + 4);
        const float4 hC = *(const float4*)(hcs + lane * 16 + 8);
        const float4 hD = *(const float4*)(hcs + lane * 16 + 12);

        float accs[8];
        #pragma unroll
        for (int bq = 0; bq < 2; bq++) {
            int4 qv[4];
            #pragma unroll
            for (int i = 0; i < 4; i++) {
                const int rl = (bq * 4 + i) * 16 + wave;
                const int row = b * RPB + (rl < RPB ? rl : 0);
                qv[i] = *(const int4*)(wq8 + (size_t)row * H + lane * 16);
            }
            #pragma unroll
            for (int i = 0; i < 4; i++) {
                const int4 q = qv[i];
                float a;
                a  = sb2f(q.x, 0) * hA.x + sb2f(q.x, 1) * hA.y + sb2f(q.x, 2) * hA.z + sb2f(q.x, 3) * hA.w;
                a += sb2f(q.y, 0) * hB.x + sb2f(q.y, 1) * hB.y + sb2f(q.y, 2) * hB.z + sb2f(q.y, 3) * hB.w;
                a += sb2f(q.z, 0) * hC.x + sb2f(q.z, 1) * hC.y + sb2f(q.z, 2) * hC.z + sb2f(q.z, 3) * hC.w;
                a += sb2f(q.w, 0) * hD.x + sb2f(q.w, 1) * hD.y + sb2f(q.w, 2) * hD.z + sb2f(q.w, 3) * hD.w;
                accs[bq * 4 + i] = a;
            }
        }
        #pragma unroll
        for (int off = 32; off > 0; off >>= 1) {
            #pragma unroll
            for (int i = 0; i < 8; i++) accs[i] += __shfl_down(accs[i], off);
        }
        if (lane == 0) {
            #pragma unroll
            for (int i = 0; i < 8; i++) {
                const int rl = i * 16 + wave;
                if (rl < RPB) {
                    const int row = b * RPB + rl;
                    const float2 se = scl_eps[row];
                    float p = se.x * accs[i] + b_fc[row];
                    p = fmaxf(p, 0.f);
                    const float e = se.y * Hl2;   // Cauchy-Schwarz, relu 1-Lipschitz
                    ub[rl] = p + e;
                    lb[rl] = p - e;
                }
            }
        }
        __syncthreads();

        if (wave == 0) {
            float m = fmaxf(lb[lane], lb[lane + 64]);
            m = wave_reduce_max(m);
            if (lane == 0) LBmax_s = m;
        }
        // next-step u1 partial from hcs (h1 of this step), into carried reg
        accU = 0.f;
        #pragma unroll
        for (int k = 0; k < 4; k++) accU += dot4(wu[k], hcs, k * 256 + lane * 4);
        __syncthreads();
        const float LBmax = LBmax_s;

        unsigned long long bestKey = 0ull;
        #pragma unroll
        for (int i = 0; i < 8; i++) {
            const int rl = i * 16 + wave;
            if (rl >= RPB) break;
            if (ub[rl] >= LBmax) {          // wave-uniform
                const int row = b * RPB + rl;
                const float* wrow = w_fc + (size_t)row * H;
                float a = 0.f;
                #pragma unroll
                for (int k = 0; k < 4; k++) {
                    const int c = k * 256 + lane * 4;
                    a += dot4(*(const float4*)(wrow + c), hcs, c);
                }
                a = wave_reduce_sum(a);
                if (lane == 0) {
                    float p = a + b_fc[row];
                    p = p > 0.f ? p : 0.f;
                    const unsigned long long key =
                        ((unsigned long long)__float_as_uint(p) << 32) |
                        (0xFFFFFFFFu - (unsigned int)row);
                    if (key > bestKey) bestKey = key;
                }
            }
        }
        if (lane == 0) wkey[wave] = bestKey;
        __syncthreads();
        if (t == 0) {
            unsigned long long k2 = wkey[0];
            #pragma unroll
            for (int i = 1; i < 16; i++) k2 = (wkey[i] > k2) ? wkey[i] : k2;
            stc64(&keys[b], k2);
        }
        gbar(cnt, NB * (++barK));
    }
}

// ---------------------------------------------------------------------------
// Fallback path (workspace too small): R3's launch-loop kernels.
// ---------------------------------------------------------------------------
__global__ __launch_bounds__(NT) void init_kernel(
    const int* __restrict__ y, const float* __restrict__ ctx,
    const float* __restrict__ w_hh0, const float* __restrict__ b_ih0,
    const float* __restrict__ b_hh0,
    float* __restrict__ v0, float* __restrict__ c0, float* __restrict__ c1,
    float* __restrict__ h1g0, unsigned long long* __restrict__ keys)
{
    __shared__ __align__(16) float h0s[H];
    const int b = blockIdx.x, t = threadIdx.x;
    h0s[t] = ctx[t];
    __syncthreads();

    const int wave = t >> 6, lane = t & 63;
    const int rowR = (wave >> 2) * H + b * 4 + (wave & 3);
    {
        const float* w0r = w_hh0 + (size_t)rowR * H;
        float accV = 0.f;
        #pragma unroll
        for (int k = 0; k < 4; k++) {
            const int c = k * 256 + lane * 4;
            accV += dot4(*(const float4*)(w0r + c), h0s, c);
        }
        accV = wave_reduce_sum(accV);
        if (lane == 0) v0[rowR] = accV + b_ih0[rowR] + b_hh0[rowR];
    }
    if (b == 0) {
        c0[t]   = ctx[t];
        c1[t]   = ctx[H + t];
        h1g0[t] = ctx[H + t];
        if (t < NB) keys[t] = 0ull;
        if (t == 0) {
            keys[0] = ((unsigned long long)0x7F800000u << 32) |
                      (0xFFFFFFFFu - (unsigned int)y[0]);
        }
    }
}

__global__ __launch_bounds__(NT) void lstm_kernel(
    const float* __restrict__ w_ih0, const float* __restrict__ w_ih1,
    const float* __restrict__ w_hh0, const float* __restrict__ w_hh1,
    const float* __restrict__ b_ih0, const float* __restrict__ b_hh0,
    const float* __restrict__ b_ih1, const float* __restrict__ b_hh1,
    const float* __restrict__ v0_in, float* __restrict__ v0_out,
    const float* __restrict__ c0_in, float* __restrict__ c0_out,
    float* __restrict__ c1,
    const float* __restrict__ h1prev, float* __restrict__ h1out,
    const unsigned long long* __restrict__ keys)
{
    __shared__ __align__(16) float h0s[H];
    __shared__ __align__(16) float h1ps[H];
    __shared__ float g1s[16];
    __shared__ unsigned long long kred[4];
    const int b = blockIdx.x, t = threadIdx.x;
    const int wave = t >> 6, lane = t & 63;
    const int rowR = (wave >> 2) * H + b * 4 + (wave & 3);

    const float* wU = w_hh1 + (size_t)rowR * H;
    float4 wu[4];
    #pragma unroll
    for (int k = 0; k < 4; k++)
        wu[k] = *(const float4*)(wU + k * 256 + lane * 4);

    h1ps[t] = h1prev[t];

    if (wave < 4) {
        unsigned long long k = keys[t];
        k = wave_reduce_max_u64(k);
        if (lane == 0) kred[wave] = k;
    }

    const float v0a = v0_in[t],         v0b = v0_in[H + t];
    const float v0c = v0_in[2 * H + t], v0d = v0_in[3 * H + t];
    const float wia = w_ih0[t],         wib = w_ih0[H + t];
    const float wic = w_ih0[2 * H + t], wid = w_ih0[3 * H + t];
    const float c0v = c0_in[t];

    __syncthreads();

    unsigned long long kk = kred[0];
    kk = (kred[1] > kk) ? kred[1] : kk;
    kk = (kred[2] > kk) ? kred[2] : kk;
    kk = (kred[3] > kk) ? kred[3] : kk;
    const float tok =
        (float)(unsigned int)(0xFFFFFFFFu - (unsigned int)(kk & 0xFFFFFFFFull));

    float accU = 0.f;
    #pragma unroll
    for (int k = 0; k < 4; k++) {
        const int c = k * 256 + lane * 4;
        accU += dot4(wu[k], h1ps, c);
    }

    {
        const float gi = v0a + tok * wia;
        const float gf = v0b + tok * wib;
        const float gg = v0c + tok * wic;
        const float go = v0d + tok * wid;
        const float i_ = sigmoidf_(gi);
        const float f_ = sigmoidf_(gf);
        const float g_ = tanhf(gg);
        const float o_ = sigmoidf_(go);
        const float cn = f_ * c0v + i_ * g_;
        if (b == 0) c0_out[t] = cn;
        h0s[t] = o_ * tanhf(cn);
    }
    __syncthreads();

    {
        const float* wA = w_ih1 + (size_t)rowR * H;
        const float* wB = w_hh0 + (size_t)rowR * H;
        float accA = 0.f, accB = 0.f;
        #pragma unroll
        for (int k = 0; k < 4; k++) {
            const int c = k * 256 + lane * 4;
            accA += dot4(*(const float4*)(wA + c), h0s, c);
            accB += dot4(*(const float4*)(wB + c), h0s, c);
        }
        const float g  = wave_reduce_sum(accA + accU);
        const float vv = wave_reduce_sum(accB);
        if (lane == 0) {
            g1s[wave]    = g  + b_ih1[rowR] + b_hh1[rowR];
            v0_out[rowR] = vv + b_ih0[rowR] + b_hh0[rowR];
        }
    }
    __syncthreads();

    if (t < 4) {
        const float i_ = sigmoidf_(g1s[t]);
        const float f_ = sigmoidf_(g1s[4 + t]);
        const float g_ = tanhf(g1s[8 + t]);
        const float o_ = sigmoidf_(g1s[12 + t]);
        const float cn = f_ * c1[b * 4 + t] + i_ * g_;
        c1[b * 4 + t] = cn;
        h1out[b * 4 + t] = o_ * tanhf(cn);
    }
}

__global__ __launch_bounds__(NT) void fc32_kernel(
    const float* __restrict__ w_fc, const float* __restrict__ b_fc,
    const float* __restrict__ h1cur, unsigned long long* __restrict__ keys,
    float* __restrict__ out_row)
{
    __shared__ __align__(16) float h1s[H];
    __shared__ unsigned long long wkey[16];
    const int b = blockIdx.x, t = threadIdx.x;
    const int wave = t >> 6, lane = t & 63;

    h1s[t] = h1cur[t];
    __syncthreads();

    unsigned long long bestKey = 0ull;
    #pragma unroll
    for (int i = 0; i < 8; i++) {
        const int rl = i * 16 + wave;
        if (rl >= RPB) break;
        const int row = b * RPB + rl;
        const float* wrow = w_fc + (size_t)row * H;
        float a = 0.f;
        #pragma unroll
        for (int k = 0; k < 4; k++) {
            const int c = k * 256 + lane * 4;
            a += dot4(*(const float4*)(wrow + c), h1s, c);
        }
        a = wave_reduce_sum(a);
        if (lane == 0) {
            float p = a + b_fc[row];
            p = p > 0.f ? p : 0.f;
            out_row[row] = p;
            const unsigned long long key =
                ((unsigned long long)__float_as_uint(p) << 32) |
                (0xFFFFFFFFu - (unsigned int)row);
            if (key > bestKey) bestKey = key;
        }
    }

    if (lane == 0) wkey[wave] = bestKey;
    __syncthreads();
    if (t == 0) {
        unsigned long long k = wkey[0];
        #pragma unroll
        for (int i = 1; i < 16; i++) k = (wkey[i] > k) ? wkey[i] : k;
        keys[b] = k;
    }
}

// ---------------------------------------------------------------------------
// Final batched exact FC: out[t] = relu(W_fc @ h1_hist[t] + b), t = 1..L-1.
// ---------------------------------------------------------------------------
__global__ __launch_bounds__(GT) void out_gemm(
    const float* __restrict__ w_fc, const float* __restrict__ b_fc,
    const float* __restrict__ h1_hist, float* __restrict__ out)
{
    __shared__ __align__(16) float hs[GS][H];       // 32 KB
    __shared__ float stage[GS][64];                 // 2 KB
    const int b = blockIdx.x, t = threadIdx.x;
    const int wave = t >> 6, lane = t & 63;
    const int row0 = b * 64 + wave * GR;

    float4 wr[GR][4];
    #pragma unroll
    for (int r = 0; r < GR; r++)
        #pragma unroll
        for (int k = 0; k < 4; k++)
            wr[r][k] = *(const float4*)(w_fc + (size_t)(row0 + r) * H + k * 256 + lane * 4);

    for (int chunk = 0; chunk < NCHUNK; ++chunk) {
        __syncthreads();
        {
            const float4* src = (const float4*)(h1_hist + (size_t)chunk * GS * H);
            float4* dsts = (float4*)(&hs[0][0]);
            #pragma unroll
            for (int j = 0; j < 4; j++) dsts[j * GT + t] = src[j * GT + t];
        }
        __syncthreads();

        #pragma unroll
        for (int sb = 0; sb < 2; sb++) {
            float acc[GR][4];
            #pragma unroll
            for (int r = 0; r < GR; r++)
                #pragma unroll
                for (int s = 0; s < 4; s++) acc[r][s] = 0.f;
            #pragma unroll
            for (int k = 0; k < 4; k++) {
                const int c = k * 256 + lane * 4;
                const float4 h0 = *(const float4*)(&hs[sb * 4 + 0][c]);
                const float4 h1 = *(const float4*)(&hs[sb * 4 + 1][c]);
                const float4 h2 = *(const float4*)(&hs[sb * 4 + 2][c]);
                const float4 h3 = *(const float4*)(&hs[sb * 4 + 3][c]);
                #pragma unroll
                for (int r = 0; r < GR; r++) {
                    const float4 w = wr[r][k];
                    acc[r][0] += w.x * h0.x + w.y * h0.y + w.z * h0.z + w.w * h0.w;
                    acc[r][1] += w.x * h1.x + w.y * h1.y + w.z * h1.z + w.w * h1.w;
                    acc[r][2] += w.x * h2.x + w.y * h2.y + w.z * h2.z + w.w * h2.w;
                    acc[r][3] += w.x * h3.x + w.y * h3.y + w.z * h3.z + w.w * h3.w;
                }
            }
            #pragma unroll
            for (int r = 0; r < GR; r++)
                #pragma unroll
                for (int s = 0; s < 4; s++) {
                    const float vv = wave_reduce_sum(acc[r][s]);
                    if (lane == 0) stage[sb * 4 + s][wave * GR + r] = vv;
                }
        }
        __syncthreads();
        {
            const int s = t >> 6;              // 0..7
            const int col = t & 63;
            const int sidx = chunk * GS + s;
            if (sidx >= 1) {
                const float vv = stage[s][col] + b_fc[b * 64 + col];
                out[(size_t)sidx * V + b * 64 + col] = fmaxf(vv, 0.f);
            }
        }
    }
}

// ---------------------------------------------------------------------------
// Host launcher
// ---------------------------------------------------------------------------
extern "C" void kernel_launch(void* const* d_in, const int* in_sizes, int n_in,
                              void* d_out, int out_size, void* d_ws, size_t ws_size,
                              hipStream_t stream)
{
    const int*   y     = (const int*)  d_in[0];
    const float* ctx   = (const float*)d_in[1];
    const float* w_ih0 = (const float*)d_in[2];
    const float* w_hh0 = (const float*)d_in[3];
    const float* b_ih0 = (const float*)d_in[4];
    const float* b_hh0 = (const float*)d_in[5];
    const float* w_ih1 = (const float*)d_in[6];
    const float* w_hh1 = (const float*)d_in[7];
    const float* b_ih1 = (const float*)d_in[8];
    const float* b_hh1 = (const float*)d_in[9];
    const float* w_fc  = (const float*)d_in[10];
    const float* b_fc  = (const float*)d_in[11];
    float* out = (float*)d_out;

    const size_t WQ8_BYTES  = (size_t)V * H;                 // 32,768,000
    const size_t SCL_BYTES  = (size_t)V * sizeof(float2);    // 256,000
    const size_t HIST_BYTES = (size_t)L * H * sizeof(float); // 8,388,608
    const size_t STATE_BYTES = 55808;
    const int use8 = (ws_size >= WQ8_BYTES + SCL_BYTES + HIST_BYTES + STATE_BYTES) ? 1 : 0;

    char* ws = (char*)d_ws;
    signed char* wq8     = (signed char*)ws;
    float2*      scl_eps = (float2*)(ws + WQ8_BYTES);
    float*       h1_hist = (float*)(ws + WQ8_BYTES + SCL_BYTES);
    char* base = ws + (use8 ? (WQ8_BYTES + SCL_BYTES + HIST_BYTES) : 0);
    float* v0g = (float*)(base + 0);                                // [2][4096]
    float* c0  = (float*)(base + 32768);                            // [2][1024] (fallback)
    float* c1  = (float*)(base + 40960);                            // [1024]    (fallback)
    float* h1g = (float*)(base + 45056);                            // [2][1024]
    unsigned long long* keys = (unsigned long long*)(base + 53248); // [256]
    unsigned int* cnt = (unsigned int*)(base + 55296);              // barrier counter

    // out row 0 is defined as zeros
    hipMemsetAsync(d_out, 0, (size_t)V * sizeof(float), stream);

    if (use8) {
        hipMemsetAsync(cnt, 0, 256, stream);   // must be re-zeroed every run
        hipMemsetAsync(h1_hist, 0, (size_t)H * sizeof(float), stream);
        quant_fc<<<512, 256, 0, stream>>>(w_fc, wq8, scl_eps);
        persistent_kernel<<<NB, NT, 0, stream>>>(
            y, ctx, w_ih0, w_ih1, w_hh0, w_hh1,
            b_ih0, b_hh0, b_ih1, b_hh1,
            wq8, scl_eps, w_fc, b_fc,
            v0g, h1g, keys, cnt, h1_hist);
        out_gemm<<<GNB, GT, 0, stream>>>(w_fc, b_fc, h1_hist, out);
    } else {
        init_kernel<<<NB, NT, 0, stream>>>(y, ctx, w_hh0, b_ih0, b_hh0,
                                           v0g, c0, c1, h1g /*buf0*/, keys);
        for (int t = 1; t < L; t++) {
            const float* v0i = v0g + ((t - 1) & 1) * G4;
            float*       v0o = v0g + (t & 1) * G4;
            const float* c0i = c0 + ((t - 1) & 1) * H;
            float*       c0o = c0 + (t & 1) * H;
            const float* h1p = h1g + ((t - 1) & 1) * H;
            float*       h1c = h1g + (t & 1) * H;
            lstm_kernel<<<NB, NT, 0, stream>>>(w_ih0, w_ih1, w_hh0, w_hh1,
                                               b_ih0, b_hh0, b_ih1, b_hh1,
                                               v0i, v0o, c0i, c0o, c1,
                                               h1p, h1c, keys);
            fc32_kernel<<<NB, NT, 0, stream>>>(w_fc, b_fc, h1c, keys,
                                               out + (size_t)t * V);
        }
    }
}

// Round 6
// 111904.712 us; speedup vs baseline: 1.1779x; 1.1779x over previous
//
#include <hip/hip_runtime.h>
#include <cstdint>
#include <cstddef>

#define H   1024
#define V   32000
#define L   2048
#define G4  4096      // 4*H
#define NB  256       // blocks (1 per CU, co-resident)
#define NT  1024      // threads per block (16 waves of 64)
#define RPB (V / NB)  // 125 FC rows per block

// final-GEMM config
#define GNB   500     // 32000 / 64 rows per block
#define GT    512     // threads (8 waves)
#define GS    8       // steps per chunk
#define GR    8       // rows per wave
#define NCHUNK (L / GS)  // 256

// ---------------------------------------------------------------------------
__device__ __forceinline__ float wave_reduce_sum(float v) {
    #pragma unroll
    for (int off = 32; off > 0; off >>= 1) v += __shfl_down(v, off);
    return v;
}

__device__ __forceinline__ float wave_reduce_max(float v) {
    #pragma unroll
    for (int off = 32; off > 0; off >>= 1) v = fmaxf(v, __shfl_down(v, off));
    return v;
}

__device__ __forceinline__ unsigned long long wave_reduce_max_u64(unsigned long long v) {
    #pragma unroll
    for (int off = 32; off > 0; off >>= 1) {
        const unsigned long long o = __shfl_down(v, off);
        v = (o > v) ? o : v;
    }
    return v;
}

__device__ __forceinline__ float sigmoidf_(float x) {
    return 1.0f / (1.0f + expf(-x));
}

__device__ __forceinline__ float dot4(const float4 w, const float* __restrict__ h, int c) {
    return w.x * h[c] + w.y * h[c + 1] + w.z * h[c + 2] + w.w * h[c + 3];
}

// sign-extend byte `pos` of dword w to float
__device__ __forceinline__ float sb2f(int w, int pos) {
    return (float)((w << ((3 - pos) * 8)) >> 24);
}

// ---------------------------------------------------------------------------
// Per-access device-coherent loads/stores (line-granular, no cache-wide
// invalidates). Protocol functionally PROVEN in R5 (absmax bit-matched the
// launch-loop version).
// ---------------------------------------------------------------------------
__device__ __forceinline__ float ldc(const float* p) {
    return __hip_atomic_load(p, __ATOMIC_RELAXED, __HIP_MEMORY_SCOPE_AGENT);
}
__device__ __forceinline__ void stc(float* p, float v) {
    __hip_atomic_store(p, v, __ATOMIC_RELAXED, __HIP_MEMORY_SCOPE_AGENT);
}
__device__ __forceinline__ unsigned long long ldc64(const unsigned long long* p) {
    return __hip_atomic_load(p, __ATOMIC_RELAXED, __HIP_MEMORY_SCOPE_AGENT);
}
__device__ __forceinline__ void stc64(unsigned long long* p, unsigned long long v) {
    __hip_atomic_store(p, v, __ATOMIC_RELAXED, __HIP_MEMORY_SCOPE_AGENT);
}

// ---------------------------------------------------------------------------
// Hierarchical fence-free grid barrier (monotonic counters, barrier index k).
// Stage 1: 32-way RMW on 8 distinct group lines; stage 2: 8-way on global;
// stage 3: per-group release line (31 read-only spinners each).
// Layout (uint index into bar): gcnt[g] at g*32, gl at 256, grel[g] at 288+g*32
// (all 128 B apart). __syncthreads() before arrival drains each wave's VMEM
// (compiler emits s_waitcnt vmcnt(0) pre-s_barrier) => prior sc1 stores are at
// the coherence point before the counter bump is visible.
// ---------------------------------------------------------------------------
__device__ __forceinline__ void gbar2(unsigned int* bar, unsigned int k, int b) {
    __syncthreads();
    if (threadIdx.x == 0) {
        const int g = b >> 5;                       // 8 groups of 32 blocks
        unsigned int* gcnt = bar + g * 32;
        unsigned int* gl   = bar + 256;
        unsigned int* grel = bar + 288 + g * 32;
        __hip_atomic_fetch_add(gcnt, 1u, __ATOMIC_RELAXED, __HIP_MEMORY_SCOPE_AGENT);
        if ((b & 31) == 0) {
            while (__hip_atomic_load(gcnt, __ATOMIC_RELAXED, __HIP_MEMORY_SCOPE_AGENT) < 32u * k)
                __builtin_amdgcn_s_sleep(2);
            __hip_atomic_fetch_add(gl, 1u, __ATOMIC_RELAXED, __HIP_MEMORY_SCOPE_AGENT);
            while (__hip_atomic_load(gl, __ATOMIC_RELAXED, __HIP_MEMORY_SCOPE_AGENT) < 8u * k)
                __builtin_amdgcn_s_sleep(2);
            __hip_atomic_store(grel, k, __ATOMIC_RELAXED, __HIP_MEMORY_SCOPE_AGENT);
        } else {
            while (__hip_atomic_load(grel, __ATOMIC_RELAXED, __HIP_MEMORY_SCOPE_AGENT) < k)
                __builtin_amdgcn_s_sleep(2);
        }
    }
    __syncthreads();
}

// ---------------------------------------------------------------------------
// One-time: w_fc fp32 -> per-row-scaled int8 + exact quant-error L2 norm.
// ---------------------------------------------------------------------------
__global__ __launch_bounds__(256) void quant_fc(
    const float* __restrict__ src, signed char* __restrict__ dst,
    float2* __restrict__ scl_eps)
{
    const int gw   = (blockIdx.x * blockDim.x + threadIdx.x) >> 6;
    const int lane = threadIdx.x & 63;
    const int nw   = (gridDim.x * blockDim.x) >> 6;
    for (int row = gw; row < V; row += nw) {
        const float* p = src + (size_t)row * H + lane * 16;
        float w[16];
        #pragma unroll
        for (int j = 0; j < 4; j++) {
            const float4 f = *(const float4*)(p + j * 4);
            w[j * 4 + 0] = f.x; w[j * 4 + 1] = f.y;
            w[j * 4 + 2] = f.z; w[j * 4 + 3] = f.w;
        }
        float m = 0.f;
        #pragma unroll
        for (int j = 0; j < 16; j++) m = fmaxf(m, fabsf(w[j]));
        m = wave_reduce_max(m);
        m = __shfl(m, 0);
        const float scale = fmaxf(m, 1e-30f) / 127.f;
        const float inv   = 127.f / fmaxf(m, 1e-30f);
        int q[16];
        float esq = 0.f;
        #pragma unroll
        for (int j = 0; j < 16; j++) {
            q[j] = __float2int_rn(w[j] * inv);
            const float e = w[j] - scale * (float)q[j];
            esq += e * e;
        }
        esq = wave_reduce_sum(esq);
        const unsigned int d0 = (q[0] & 255) | ((q[1] & 255) << 8) | ((q[2] & 255) << 16) | ((unsigned int)(q[3] & 255) << 24);
        const unsigned int d1 = (q[4] & 255) | ((q[5] & 255) << 8) | ((q[6] & 255) << 16) | ((unsigned int)(q[7] & 255) << 24);
        const unsigned int d2 = (q[8] & 255) | ((q[9] & 255) << 8) | ((q[10] & 255) << 16) | ((unsigned int)(q[11] & 255) << 24);
        const unsigned int d3 = (q[12] & 255) | ((q[13] & 255) << 8) | ((q[14] & 255) << 16) | ((unsigned int)(q[15] & 255) << 24);
        *(int4*)(dst + (size_t)row * H + lane * 16) =
            make_int4((int)d0, (int)d1, (int)d2, (int)d3);
        if (lane == 0) {
            scl_eps[row] = make_float2(scale, sqrtf(esq) + 1e-12f);
        }
    }
}

// ---------------------------------------------------------------------------
// Persistent kernel, attempt #3: __launch_bounds__(NT, 4) forces the 128-VGPR
// budget so the 48 persistent weight VGPRs actually STAY in registers
// (R5's 64-VGPR allocation spilled them to scratch => 73 MB/step HBM).
// ---------------------------------------------------------------------------
__global__ __launch_bounds__(NT, 4) void persistent_kernel(
    const int* __restrict__ y, const float* __restrict__ ctx,
    const float* __restrict__ w_ih0, const float* __restrict__ w_ih1,
    const float* __restrict__ w_hh0, const float* __restrict__ w_hh1,
    const float* __restrict__ b_ih0, const float* __restrict__ b_hh0,
    const float* __restrict__ b_ih1, const float* __restrict__ b_hh1,
    const signed char* __restrict__ wq8, const float2* __restrict__ scl_eps,
    const float* __restrict__ w_fc, const float* __restrict__ b_fc,
    float* __restrict__ v0g, float* __restrict__ h1g,
    unsigned long long* __restrict__ keys, unsigned int* __restrict__ bar,
    float* __restrict__ h1_hist)
{
    __shared__ __align__(16) float h0s[H];
    __shared__ __align__(16) float hcs[H];
    __shared__ float g1s[16];
    __shared__ unsigned long long kred[4];
    __shared__ float lb[128], ub[128];
    __shared__ float red[16];
    __shared__ float LBmax_s;
    __shared__ unsigned long long wkey[16];
    __shared__ float c1s[4];

    const int b = blockIdx.x, t = threadIdx.x;
    const int wave = t >> 6, lane = t & 63;
    const int rowR = (wave >> 2) * H + b * 4 + (wave & 3);

    unsigned int barK = 0;

    // ---- persistent register state: this wave's 3 LSTM weight rows ----
    float4 wu[4], wa[4], wb[4];
    #pragma unroll
    for (int k = 0; k < 4; k++) {
        const int c = k * 256 + lane * 4;
        wu[k] = *(const float4*)(w_hh1 + (size_t)rowR * H + c);
        wa[k] = *(const float4*)(w_ih1 + (size_t)rowR * H + c);
        wb[k] = *(const float4*)(w_hh0 + (size_t)rowR * H + c);
    }
    const float wia = w_ih0[t],         wib = w_ih0[H + t];
    const float wic = w_ih0[2 * H + t], wid = w_ih0[3 * H + t];
    const float bias0 = b_ih0[rowR] + b_hh0[rowR];
    const float bias1 = b_ih1[rowR] + b_hh1[rowR];
    float c0_reg = ctx[t];                 // block-redundant c0 in register

    // ---- prologue: v0 buffer0, accU for step 1, c1, keys seed ----
    h0s[t] = ctx[t];
    hcs[t] = ctx[H + t];
    if (t < 4) c1s[t] = ctx[H + b * 4 + t];
    __syncthreads();
    {
        float accV = 0.f;
        #pragma unroll
        for (int k = 0; k < 4; k++) accV += dot4(wb[k], h0s, k * 256 + lane * 4);
        accV = wave_reduce_sum(accV);
        if (lane == 0) stc(&v0g[rowR], accV + bias0);   // buffer 0
    }
    float accU = 0.f;                      // per-lane u1 partial, carried in reg
    #pragma unroll
    for (int k = 0; k < 4; k++) accU += dot4(wu[k], hcs, k * 256 + lane * 4);
    if (b == 0 && t < NB) {
        const unsigned long long seed =
            ((unsigned long long)0x7F800000u << 32) |
            (0xFFFFFFFFu - (unsigned int)y[0]);
        stc64(&keys[t], (t == 0) ? seed : 0ull);
    }
    gbar2(bar, ++barK, b);

    // ---------------- main loop ----------------
    for (int step = 1; step < L; ++step) {
        const float* v0i = v0g + ((step - 1) & 1) * G4;
        float*       v0o = v0g + (step & 1) * G4;
        float*       h1c = h1g + (step & 1) * H;

        // ======== phase A: lstm ========
        if (wave < 4) {
            unsigned long long k = ldc64(&keys[t]);     // t < 256
            k = wave_reduce_max_u64(k);
            if (lane == 0) kred[wave] = k;
        }
        const float v0a = ldc(&v0i[t]);
        const float v0b = ldc(&v0i[H + t]);
        const float v0c = ldc(&v0i[2 * H + t]);
        const float v0d = ldc(&v0i[3 * H + t]);
        __syncthreads();

        unsigned long long kk = kred[0];
        kk = (kred[1] > kk) ? kred[1] : kk;
        kk = (kred[2] > kk) ? kred[2] : kk;
        kk = (kred[3] > kk) ? kred[3] : kk;
        const float tok =
            (float)(unsigned int)(0xFFFFFFFFu - (unsigned int)(kk & 0xFFFFFFFFull));

        // cell0 (block-redundant), element j = t; c0 in register
        {
            const float gi = v0a + tok * wia;
            const float gf = v0b + tok * wib;
            const float gg = v0c + tok * wic;
            const float go = v0d + tok * wid;
            const float i_ = sigmoidf_(gi);
            const float f_ = sigmoidf_(gf);
            const float g_ = tanhf(gg);
            const float o_ = sigmoidf_(go);
            const float cn = f_ * c0_reg + i_ * g_;
            c0_reg = cn;
            h0s[t] = o_ * tanhf(cn);
        }
        __syncthreads();

        // per wave: g1 row (reg w_ih1 @ h0 + carried accU), v0 row (reg w_hh0 @ h0)
        {
            float accA = 0.f, accB = 0.f;
            #pragma unroll
            for (int k = 0; k < 4; k++) {
                const int c = k * 256 + lane * 4;
                accA += dot4(wa[k], h0s, c);
                accB += dot4(wb[k], h0s, c);
            }
            const float g  = wave_reduce_sum(accA + accU);
            const float vv = wave_reduce_sum(accB);
            if (lane == 0) {
                g1s[wave] = g + bias1;
                stc(&v0o[rowR], vv + bias0);
            }
        }
        __syncthreads();

        // cell1: this block's 4 elements
        if (t < 4) {
            const float i_ = sigmoidf_(g1s[t]);
            const float f_ = sigmoidf_(g1s[4 + t]);
            const float g_ = tanhf(g1s[8 + t]);
            const float o_ = sigmoidf_(g1s[12 + t]);
            const float cn = f_ * c1s[t] + i_ * g_;
            c1s[t] = cn;
            const float hv = o_ * tanhf(cn);
            stc(&h1c[b * 4 + t], hv);
            h1_hist[(size_t)step * H + b * 4 + t] = hv;
        }
        gbar2(bar, ++barK, b);

        // ======== phase B: int8 screen + sound rescue ========
        if (t < 128) { lb[t] = -3e38f; ub[t] = -3e38f; }
        const float hv2 = ldc(&h1c[t]);
        hcs[t] = hv2;
        {
            const float sq = wave_reduce_sum(hv2 * hv2);
            if (lane == 0) red[wave] = sq;
        }
        __syncthreads();

        float s = 0.f;
        #pragma unroll
        for (int i = 0; i < 16; i++) s += red[i];
        const float Hl2 = sqrtf(s);

        const float4 hA = *(const float4*)(hcs + lane * 16);
        const float4 hB = *(const float4*)(hcs + lane * 16 + 4);
        const float4 hC = *(const float4*)(hcs + lane * 16 + 8);
        const float4 hD = *(const float4*)(hcs + lane * 16 + 12);

        float accs[8];
        #pragma unroll
        for (int bq = 0; bq < 2; bq++) {
            int4 qv[4];
            #pragma unroll
            for (int i = 0; i < 4; i++) {
                const int rl = (bq * 4 + i) * 16 + wave;
                const int row = b * RPB + (rl < RPB ? rl : 0);
                qv[i] = *(const int4*)(wq8 + (size_t)row * H + lane * 16);
            }
            #pragma unroll
            for (int i = 0; i < 4; i++) {
                const int4 q = qv[i];
                float a;
                a  = sb2f(q.x, 0) * hA.x + sb2f(q.x, 1) * hA.y + sb2f(q.x, 2) * hA.z + sb2f(q.x, 3) * hA.w;
                a += sb2f(q.y, 0) * hB.x + sb2f(q.y, 1) * hB.y + sb2f(q.y, 2) * hB.z + sb2f(q.y, 3) * hB.w;
                a += sb2f(q.z, 0) * hC.x + sb2f(q.z, 1) * hC.y + sb2f(q.z, 2) * hC.z + sb2f(q.z, 3) * hC.w;
                a += sb2f(q.w, 0) * hD.x + sb2f(q.w, 1) * hD.y + sb2f(q.w, 2) * hD.z + sb2f(q.w, 3) * hD.w;
                accs[bq * 4 + i] = a;
            }
        }
        #pragma unroll
        for (int off = 32; off > 0; off >>= 1) {
            #pragma unroll
            for (int i = 0; i < 8; i++) accs[i] += __shfl_down(accs[i], off);
        }
        if (lane == 0) {
            #pragma unroll
            for (int i = 0; i < 8; i++) {
                const int rl = i * 16 + wave;
                if (rl < RPB) {
                    const int row = b * RPB + rl;
                    const float2 se = scl_eps[row];
                    float p = se.x * accs[i] + b_fc[row];
                    p = fmaxf(p, 0.f);
                    const float e = se.y * Hl2;   // Cauchy-Schwarz, relu 1-Lipschitz
                    ub[rl] = p + e;
                    lb[rl] = p - e;
                }
            }
        }
        __syncthreads();

        if (wave == 0) {
            float m = fmaxf(lb[lane], lb[lane + 64]);
            m = wave_reduce_max(m);
            if (lane == 0) LBmax_s = m;
        }
        // next-step u1 partial from hcs (h1 of this step), into carried reg
        accU = 0.f;
        #pragma unroll
        for (int k = 0; k < 4; k++) accU += dot4(wu[k], hcs, k * 256 + lane * 4);
        __syncthreads();
        const float LBmax = LBmax_s;

        unsigned long long bestKey = 0ull;
        #pragma unroll
        for (int i = 0; i < 8; i++) {
            const int rl = i * 16 + wave;
            if (rl >= RPB) break;
            if (ub[rl] >= LBmax) {          // wave-uniform
                const int row = b * RPB + rl;
                const float* wrow = w_fc + (size_t)row * H;
                float a = 0.f;
                #pragma unroll
                for (int k = 0; k < 4; k++) {
                    const int c = k * 256 + lane * 4;
                    a += dot4(*(const float4*)(wrow + c), hcs, c);
                }
                a = wave_reduce_sum(a);
                if (lane == 0) {
                    float p = a + b_fc[row];
                    p = p > 0.f ? p : 0.f;
                    const unsigned long long key =
                        ((unsigned long long)__float_as_uint(p) << 32) |
                        (0xFFFFFFFFu - (unsigned int)row);
                    if (key > bestKey) bestKey = key;
                }
            }
        }
        if (lane == 0) wkey[wave] = bestKey;
        __syncthreads();
        if (t == 0) {
            unsigned long long k2 = wkey[0];
            #pragma unroll
            for (int i = 1; i < 16; i++) k2 = (wkey[i] > k2) ? wkey[i] : k2;
            stc64(&keys[b], k2);
        }
        gbar2(bar, ++barK, b);
    }
}

// ---------------------------------------------------------------------------
// Fallback path (workspace too small): R3's launch-loop kernels.
// ---------------------------------------------------------------------------
__global__ __launch_bounds__(NT) void init_kernel(
    const int* __restrict__ y, const float* __restrict__ ctx,
    const float* __restrict__ w_hh0, const float* __restrict__ b_ih0,
    const float* __restrict__ b_hh0,
    float* __restrict__ v0, float* __restrict__ c0, float* __restrict__ c1,
    float* __restrict__ h1g0, unsigned long long* __restrict__ keys)
{
    __shared__ __align__(16) float h0s[H];
    const int b = blockIdx.x, t = threadIdx.x;
    h0s[t] = ctx[t];
    __syncthreads();

    const int wave = t >> 6, lane = t & 63;
    const int rowR = (wave >> 2) * H + b * 4 + (wave & 3);
    {
        const float* w0r = w_hh0 + (size_t)rowR * H;
        float accV = 0.f;
        #pragma unroll
        for (int k = 0; k < 4; k++) {
            const int c = k * 256 + lane * 4;
            accV += dot4(*(const float4*)(w0r + c), h0s, c);
        }
        accV = wave_reduce_sum(accV);
        if (lane == 0) v0[rowR] = accV + b_ih0[rowR] + b_hh0[rowR];
    }
    if (b == 0) {
        c0[t]   = ctx[t];
        c1[t]   = ctx[H + t];
        h1g0[t] = ctx[H + t];
        if (t < NB) keys[t] = 0ull;
        if (t == 0) {
            keys[0] = ((unsigned long long)0x7F800000u << 32) |
                      (0xFFFFFFFFu - (unsigned int)y[0]);
        }
    }
}

__global__ __launch_bounds__(NT) void lstm_kernel(
    const float* __restrict__ w_ih0, const float* __restrict__ w_ih1,
    const float* __restrict__ w_hh0, const float* __restrict__ w_hh1,
    const float* __restrict__ b_ih0, const float* __restrict__ b_hh0,
    const float* __restrict__ b_ih1, const float* __restrict__ b_hh1,
    const float* __restrict__ v0_in, float* __restrict__ v0_out,
    const float* __restrict__ c0_in, float* __restrict__ c0_out,
    float* __restrict__ c1,
    const float* __restrict__ h1prev, float* __restrict__ h1out,
    const unsigned long long* __restrict__ keys)
{
    __shared__ __align__(16) float h0s[H];
    __shared__ __align__(16) float h1ps[H];
    __shared__ float g1s[16];
    __shared__ unsigned long long kred[4];
    const int b = blockIdx.x, t = threadIdx.x;
    const int wave = t >> 6, lane = t & 63;
    const int rowR = (wave >> 2) * H + b * 4 + (wave & 3);

    const float* wU = w_hh1 + (size_t)rowR * H;
    float4 wu[4];
    #pragma unroll
    for (int k = 0; k < 4; k++)
        wu[k] = *(const float4*)(wU + k * 256 + lane * 4);

    h1ps[t] = h1prev[t];

    if (wave < 4) {
        unsigned long long k = keys[t];
        k = wave_reduce_max_u64(k);
        if (lane == 0) kred[wave] = k;
    }

    const float v0a = v0_in[t],         v0b = v0_in[H + t];
    const float v0c = v0_in[2 * H + t], v0d = v0_in[3 * H + t];
    const float wia = w_ih0[t],         wib = w_ih0[H + t];
    const float wic = w_ih0[2 * H + t], wid = w_ih0[3 * H + t];
    const float c0v = c0_in[t];

    __syncthreads();

    unsigned long long kk = kred[0];
    kk = (kred[1] > kk) ? kred[1] : kk;
    kk = (kred[2] > kk) ? kred[2] : kk;
    kk = (kred[3] > kk) ? kred[3] : kk;
    const float tok =
        (float)(unsigned int)(0xFFFFFFFFu - (unsigned int)(kk & 0xFFFFFFFFull));

    float accU = 0.f;
    #pragma unroll
    for (int k = 0; k < 4; k++) {
        const int c = k * 256 + lane * 4;
        accU += dot4(wu[k], h1ps, c);
    }

    {
        const float gi = v0a + tok * wia;
        const float gf = v0b + tok * wib;
        const float gg = v0c + tok * wic;
        const float go = v0d + tok * wid;
        const float i_ = sigmoidf_(gi);
        const float f_ = sigmoidf_(gf);
        const float g_ = tanhf(gg);
        const float o_ = sigmoidf_(go);
        const float cn = f_ * c0v + i_ * g_;
        if (b == 0) c0_out[t] = cn;
        h0s[t] = o_ * tanhf(cn);
    }
    __syncthreads();

    {
        const float* wA = w_ih1 + (size_t)rowR * H;
        const float* wB = w_hh0 + (size_t)rowR * H;
        float accA = 0.f, accB = 0.f;
        #pragma unroll
        for (int k = 0; k < 4; k++) {
            const int c = k * 256 + lane * 4;
            accA += dot4(*(const float4*)(wA + c), h0s, c);
            accB += dot4(*(const float4*)(wB + c), h0s, c);
        }
        const float g  = wave_reduce_sum(accA + accU);
        const float vv = wave_reduce_sum(accB);
        if (lane == 0) {
            g1s[wave]    = g  + b_ih1[rowR] + b_hh1[rowR];
            v0_out[rowR] = vv + b_ih0[rowR] + b_hh0[rowR];
        }
    }
    __syncthreads();

    if (t < 4) {
        const float i_ = sigmoidf_(g1s[t]);
        const float f_ = sigmoidf_(g1s[4 + t]);
        const float g_ = tanhf(g1s[8 + t]);
        const float o_ = sigmoidf_(g1s[12 + t]);
        const float cn = f_ * c1[b * 4 + t] + i_ * g_;
        c1[b * 4 + t] = cn;
        h1out[b * 4 + t] = o_ * tanhf(cn);
    }
}

__global__ __launch_bounds__(NT) void fc32_kernel(
    const float* __restrict__ w_fc, const float* __restrict__ b_fc,
    const float* __restrict__ h1cur, unsigned long long* __restrict__ keys,
    float* __restrict__ out_row)
{
    __shared__ __align__(16) float h1s[H];
    __shared__ unsigned long long wkey[16];
    const int b = blockIdx.x, t = threadIdx.x;
    const int wave = t >> 6, lane = t & 63;

    h1s[t] = h1cur[t];
    __syncthreads();

    unsigned long long bestKey = 0ull;
    #pragma unroll
    for (int i = 0; i < 8; i++) {
        const int rl = i * 16 + wave;
        if (rl >= RPB) break;
        const int row = b * RPB + rl;
        const float* wrow = w_fc + (size_t)row * H;
        float a = 0.f;
        #pragma unroll
        for (int k = 0; k < 4; k++) {
            const int c = k * 256 + lane * 4;
            a += dot4(*(const float4*)(wrow + c), h1s, c);
        }
        a = wave_reduce_sum(a);
        if (lane == 0) {
            float p = a + b_fc[row];
            p = p > 0.f ? p : 0.f;
            out_row[row] = p;
            const unsigned long long key =
                ((unsigned long long)__float_as_uint(p) << 32) |
                (0xFFFFFFFFu - (unsigned int)row);
            if (key > bestKey) bestKey = key;
        }
    }

    if (lane == 0) wkey[wave] = bestKey;
    __syncthreads();
    if (t == 0) {
        unsigned long long k = wkey[0];
        #pragma unroll
        for (int i = 1; i < 16; i++) k = (wkey[i] > k) ? wkey[i] : k;
        keys[b] = k;
    }
}

// ---------------------------------------------------------------------------
// Final batched exact FC: out[t] = relu(W_fc @ h1_hist[t] + b), t = 1..L-1.
// ---------------------------------------------------------------------------
__global__ __launch_bounds__(GT) void out_gemm(
    const float* __restrict__ w_fc, const float* __restrict__ b_fc,
    const float* __restrict__ h1_hist, float* __restrict__ out)
{
    __shared__ __align__(16) float hs[GS][H];       // 32 KB
    __shared__ float stage[GS][64];                 // 2 KB
    const int b = blockIdx.x, t = threadIdx.x;
    const int wave = t >> 6, lane = t & 63;
    const int row0 = b * 64 + wave * GR;

    float4 wr[GR][4];
    #pragma unroll
    for (int r = 0; r < GR; r++)
        #pragma unroll
        for (int k = 0; k < 4; k++)
            wr[r][k] = *(const float4*)(w_fc + (size_t)(row0 + r) * H + k * 256 + lane * 4);

    for (int chunk = 0; chunk < NCHUNK; ++chunk) {
        __syncthreads();
        {
            const float4* src = (const float4*)(h1_hist + (size_t)chunk * GS * H);
            float4* dsts = (float4*)(&hs[0][0]);
            #pragma unroll
            for (int j = 0; j < 4; j++) dsts[j * GT + t] = src[j * GT + t];
        }
        __syncthreads();

        #pragma unroll
        for (int sb = 0; sb < 2; sb++) {
            float acc[GR][4];
            #pragma unroll
            for (int r = 0; r < GR; r++)
                #pragma unroll
                for (int s = 0; s < 4; s++) acc[r][s] = 0.f;
            #pragma unroll
            for (int k = 0; k < 4; k++) {
                const int c = k * 256 + lane * 4;
                const float4 h0 = *(const float4*)(&hs[sb * 4 + 0][c]);
                const float4 h1 = *(const float4*)(&hs[sb * 4 + 1][c]);
                const float4 h2 = *(const float4*)(&hs[sb * 4 + 2][c]);
                const float4 h3 = *(const float4*)(&hs[sb * 4 + 3][c]);
                #pragma unroll
                for (int r = 0; r < GR; r++) {
                    const float4 w = wr[r][k];
                    acc[r][0] += w.x * h0.x + w.y * h0.y + w.z * h0.z + w.w * h0.w;
                    acc[r][1] += w.x * h1.x + w.y * h1.y + w.z * h1.z + w.w * h1.w;
                    acc[r][2] += w.x * h2.x + w.y * h2.y + w.z * h2.z + w.w * h2.w;
                    acc[r][3] += w.x * h3.x + w.y * h3.y + w.z * h3.z + w.w * h3.w;
                }
            }
            #pragma unroll
            for (int r = 0; r < GR; r++)
                #pragma unroll
                for (int s = 0; s < 4; s++) {
                    const float vv = wave_reduce_sum(acc[r][s]);
                    if (lane == 0) stage[sb * 4 + s][wave * GR + r] = vv;
                }
        }
        __syncthreads();
        {
            const int s = t >> 6;              // 0..7
            const int col = t & 63;
            const int sidx = chunk * GS + s;
            if (sidx >= 1) {
                const float vv = stage[s][col] + b_fc[b * 64 + col];
                out[(size_t)sidx * V + b * 64 + col] = fmaxf(vv, 0.f);
            }
        }
    }
}

// ---------------------------------------------------------------------------
// Host launcher
// ---------------------------------------------------------------------------
extern "C" void kernel_launch(void* const* d_in, const int* in_sizes, int n_in,
                              void* d_out, int out_size, void* d_ws, size_t ws_size,
                              hipStream_t stream)
{
    const int*   y     = (const int*)  d_in[0];
    const float* ctx   = (const float*)d_in[1];
    const float* w_ih0 = (const float*)d_in[2];
    const float* w_hh0 = (const float*)d_in[3];
    const float* b_ih0 = (const float*)d_in[4];
    const float* b_hh0 = (const float*)d_in[5];
    const float* w_ih1 = (const float*)d_in[6];
    const float* w_hh1 = (const float*)d_in[7];
    const float* b_ih1 = (const float*)d_in[8];
    const float* b_hh1 = (const float*)d_in[9];
    const float* w_fc  = (const float*)d_in[10];
    const float* b_fc  = (const float*)d_in[11];
    float* out = (float*)d_out;

    const size_t WQ8_BYTES  = (size_t)V * H;                 // 32,768,000
    const size_t SCL_BYTES  = (size_t)V * sizeof(float2);    // 256,000
    const size_t HIST_BYTES = (size_t)L * H * sizeof(float); // 8,388,608
    const size_t STATE_BYTES = 59392;
    const int use8 = (ws_size >= WQ8_BYTES + SCL_BYTES + HIST_BYTES + STATE_BYTES) ? 1 : 0;

    char* ws = (char*)d_ws;
    signed char* wq8     = (signed char*)ws;
    float2*      scl_eps = (float2*)(ws + WQ8_BYTES);
    float*       h1_hist = (float*)(ws + WQ8_BYTES + SCL_BYTES);
    char* base = ws + (use8 ? (WQ8_BYTES + SCL_BYTES + HIST_BYTES) : 0);
    float* v0g = (float*)(base + 0);                                // [2][4096]
    float* c0  = (float*)(base + 32768);                            // [2][1024] (fallback)
    float* c1  = (float*)(base + 40960);                            // [1024]    (fallback)
    float* h1g = (float*)(base + 45056);                            // [2][1024]
    unsigned long long* keys = (unsigned long long*)(base + 53248); // [256]
    unsigned int* bar = (unsigned int*)(base + 55296);              // 4 KB barrier area

    // out row 0 is defined as zeros
    hipMemsetAsync(d_out, 0, (size_t)V * sizeof(float), stream);

    if (use8) {
        hipMemsetAsync(bar, 0, 4096, stream);  // must be re-zeroed every run
        hipMemsetAsync(h1_hist, 0, (size_t)H * sizeof(float), stream);
        quant_fc<<<512, 256, 0, stream>>>(w_fc, wq8, scl_eps);
        persistent_kernel<<<NB, NT, 0, stream>>>(
            y, ctx, w_ih0, w_ih1, w_hh0, w_hh1,
            b_ih0, b_hh0, b_ih1, b_hh1,
            wq8, scl_eps, w_fc, b_fc,
            v0g, h1g, keys, bar, h1_hist);
        out_gemm<<<GNB, GT, 0, stream>>>(w_fc, b_fc, h1_hist, out);
    } else {
        init_kernel<<<NB, NT, 0, stream>>>(y, ctx, w_hh0, b_ih0, b_hh0,
                                           v0g, c0, c1, h1g /*buf0*/, keys);
        for (int t = 1; t < L; t++) {
            const float* v0i = v0g + ((t - 1) & 1) * G4;
            float*       v0o = v0g + (t & 1) * G4;
            const float* c0i = c0 + ((t - 1) & 1) * H;
            float*       c0o = c0 + (t & 1) * H;
            const float* h1p = h1g + ((t - 1) & 1) * H;
            float*       h1c = h1g + (t & 1) * H;
            lstm_kernel<<<NB, NT, 0, stream>>>(w_ih0, w_ih1, w_hh0, w_hh1,
                                               b_ih0, b_hh0, b_ih1, b_hh1,
                                               v0i, v0o, c0i, c0o, c1,
                                               h1p, h1c, keys);
            fc32_kernel<<<NB, NT, 0, stream>>>(w_fc, b_fc, h1c, keys,
                                               out + (size_t)t * V);
        }
    }
}